// Round 12
// baseline (233.472 us; speedup 1.0000x reference)
//
#include <hip/hip_runtime.h>
#include <stdint.h>

// Problem constants
#define B_    8
#define T_    512
#define V_    2048
#define H_    4
#define NE_   768
#define D_    8192      // V_*H_
#define PWROW 32768     // V_*H_*H_
#define M1    3072      // NE_*H_
#define K3    2048      // T_*H_
#define MTT_E 6291456UL // NE_*D_

#define AS1 __attribute__((address_space(1)))
#define AS3 __attribute__((address_space(3)))

typedef __attribute__((ext_vector_type(8))) short bf16x8;
typedef __attribute__((ext_vector_type(4))) float f32x4;

__device__ __forceinline__ unsigned short f2bf(float f) {
  union { float f; unsigned int u; } c; c.f = f;
  unsigned int u = c.u;
  return (unsigned short)((u + 0x7FFFu + ((u >> 16) & 1u)) >> 16);
}
__device__ __forceinline__ float bf2f(unsigned short s) {
  union { unsigned int u; float f; } c; c.u = ((unsigned int)s) << 16;
  return c.f;
}

#define FENCE_BAR() do { __builtin_amdgcn_sched_barrier(0); \
                         __builtin_amdgcn_s_barrier(); \
                         __builtin_amdgcn_sched_barrier(0); } while (0)

// ---------------------------------------------------------------------------
// fp32 -> bf16 convert of BOTH inputs in one launch.
// ---------------------------------------------------------------------------
__global__ __launch_bounds__(256) void cvtAB_k(
    const float* __restrict__ cooc, const float* __restrict__ pw,
    unsigned short* __restrict__ dst, int bq4, int n4) {
  int i = blockIdx.x * 256 + threadIdx.x;
  const int stride = gridDim.x * 256;
  for (; i < n4; i += stride) {
    const float4 v = (i < bq4) ? ((const float4*)cooc)[i]
                               : ((const float4*)pw)[i - bq4];
    ushort4 o;
    o.x = f2bf(v.x); o.y = f2bf(v.y); o.z = f2bf(v.z); o.w = f2bf(v.w);
    ((ushort4*)dst)[i] = o;
  }
}

// ---------------------------------------------------------------------------
// Kernel 1 (8-phase-per-2-K-tiles, 256x256, BK=64): C[m][t] over K-slice z.
// Ledger-derived port of the verified 8-phase template:
//  - LDS [2 dbuf][op][K-half][256x32] (4 x 16KB x 2ops x 2bufs = 128 KB).
//    K-half kh is read ONLY by phases {1,2} (kh=0) / {3,4} (kh=1) of its
//    tile -> each half-buffer is free 2 phases before its overwrite issue.
//  - Per tile t (buf d=t&1): P1(k0,n0) P2(k0,n1) P3(k1,n1) P4(k1,n0);
//    phase = {ds_reads; 1 half-tile prefetch issue; bar; setprio MFMA x16;
//    setprio; [vmcnt]; bar}.  Issues: P1->(t+1).A.k1  P2->(t+1).B.k1
//    P3->(t+2).A.k0  P4->(t+2).B.k0  (targets proven free above).
//  - vmcnt(8) ONLY at ends of P2 and P4 (4 half-tiles stay in flight).
//    Ledger: newest-8 at W1 = {(t+1).A.k0,B.k0,A.k1,B.k1} -> t.k1 landed
//    (needed by P3). At W2 newest-8 = {(t+1).k1, (t+2).k0} -> (t+1).k0
//    landed (needed by next P1). Last 2 tiles: vmcnt(0) (tail-safe).
//  - Swizzle: gemm1r's measured-0-conflict OFFS32 (pc = c ^ ((row>>1)&3)),
//    same involution on stage-source and ds_read.
// Accumulation order identical to gemm1p (kk=0 then kk=1 per acc element).
// Output: partial z in mtT scatter layout [e][t*4+h], bf16 ushort4 stores.
// ---------------------------------------------------------------------------
__global__ __launch_bounds__(512, 2) void gemm1e_k(
    const unsigned short* __restrict__ Aq,   // [3072][8192]
    const unsigned short* __restrict__ Bq,   // [2048][8192]
    unsigned short* __restrict__ P,          // partials, z-strided by MTT_E
    int kk_per) {
  __shared__ unsigned short lds[2][2][2][256 * 32];  // [dbuf][op][kh] 128 KB
  const int r0 = blockIdx.x * 256;   // m
  const int t0 = blockIdx.y * 256;   // t
  const int z  = blockIdx.z;
  const int kbeg = z * kk_per;
  const int NT = kk_per / 64;        // 16 at nz=8
  const int tid  = threadIdx.x;
  const int lane = tid & 63, w = tid >> 6;
  const int wm = w >> 2, wn = w & 3;
  const int fr = lane & 15, fq = lane >> 4;
  unsigned short* __restrict__ Pz = P + (size_t)z * MTT_E;

  f32x4 acc[8][4];
  #pragma unroll
  for (int m = 0; m < 8; ++m)
    #pragma unroll
    for (int n = 0; n < 4; ++n) acc[m][n] = (f32x4){0.f, 0.f, 0.f, 0.f};

  // Stage half-tile (op, kh) of the K-tile at k0 into dbuf d. 2 loads/thread.
  // chunk ci in [0,1024): row = ci>>2 in [0,256), c = ci&3,
  // source col pc = c ^ ((row>>1)&3)  (matches OFS read swizzle).
  auto SHALF = [&](int d, int op, int kh, int k0) {
    const unsigned short* G = op ? Bq : Aq;
    const int b0 = op ? t0 : r0;
    #pragma unroll
    for (int i = 0; i < 2; ++i) {
      const int ci  = i * 512 + tid;
      const int row = ci >> 2;
      const int pc  = (ci & 3) ^ ((row >> 1) & 3);
      __builtin_amdgcn_global_load_lds(
          (const AS1 void*)(G + (size_t)(b0 + row) * D_ + k0 + kh * 32 + pc * 8),
          (AS3 void*)(&lds[d][op][kh][(i * 512 + w * 64) * 8]), 16, 0, 0);
    }
  };
  // swizzled ushort offset of (row r in [0,256), chunk col c in [0,4))
  #define OFS(r, c) ((r) * 32 + ((((c) ^ (((r) >> 1) & 3))) * 8))

  // Prologue: t0 fully + t1.k0  (6 half-tiles, 12 loads); oldest 4 = t0.k0.
  SHALF(0, 0, 0, kbeg); SHALF(0, 1, 0, kbeg);
  SHALF(0, 0, 1, kbeg); SHALF(0, 1, 1, kbeg);
  SHALF(1, 0, 0, kbeg + 64); SHALF(1, 1, 0, kbeg + 64);
  asm volatile("s_waitcnt vmcnt(8)" ::: "memory");
  FENCE_BAR();

  for (int t = 0; t < NT; ++t) {
    const int d = t & 1;
    const int kn1 = kbeg + (t + 1) * 64;
    const int kn2 = kbeg + (t + 2) * 64;
    const bool i1 = (t + 1 < NT), i2 = (t + 2 < NT);
    const bool steady = (t < NT - 2);
    bf16x8 af[8], bf[2];

    // ---- P1 (kh=0, nh=0): read af(k0) + bf(n0,k0); issue (t+1).A.k1
    #pragma unroll
    for (int m = 0; m < 8; ++m)
      af[m] = *(const bf16x8*)&lds[d][0][0][OFS(wm * 128 + m * 16 + fr, fq)];
    #pragma unroll
    for (int n = 0; n < 2; ++n)
      bf[n] = *(const bf16x8*)&lds[d][1][0][OFS(wn * 64 + n * 16 + fr, fq)];
    if (i1) SHALF(d ^ 1, 0, 1, kn1);
    FENCE_BAR();
    __builtin_amdgcn_s_setprio(1);
    #pragma unroll
    for (int m = 0; m < 8; ++m)
      #pragma unroll
      for (int n = 0; n < 2; ++n)
        acc[m][n] = __builtin_amdgcn_mfma_f32_16x16x32_bf16(af[m], bf[n], acc[m][n], 0, 0, 0);
    __builtin_amdgcn_s_setprio(0);
    FENCE_BAR();

    // ---- P2 (kh=0, nh=1): read bf(n1,k0); issue (t+1).B.k1; W1
    #pragma unroll
    for (int n = 0; n < 2; ++n)
      bf[n] = *(const bf16x8*)&lds[d][1][0][OFS(wn * 64 + 32 + n * 16 + fr, fq)];
    if (i1) SHALF(d ^ 1, 1, 1, kn1);
    FENCE_BAR();
    __builtin_amdgcn_s_setprio(1);
    #pragma unroll
    for (int m = 0; m < 8; ++m)
      #pragma unroll
      for (int n = 0; n < 2; ++n)
        acc[m][n + 2] = __builtin_amdgcn_mfma_f32_16x16x32_bf16(af[m], bf[n], acc[m][n + 2], 0, 0, 0);
    __builtin_amdgcn_s_setprio(0);
    if (steady) asm volatile("s_waitcnt vmcnt(8)" ::: "memory");
    else        asm volatile("s_waitcnt vmcnt(0)" ::: "memory");
    FENCE_BAR();

    // ---- P3 (kh=1, nh=1): read af(k1) + bf(n1,k1); issue (t+2).A.k0
    #pragma unroll
    for (int m = 0; m < 8; ++m)
      af[m] = *(const bf16x8*)&lds[d][0][1][OFS(wm * 128 + m * 16 + fr, fq)];
    #pragma unroll
    for (int n = 0; n < 2; ++n)
      bf[n] = *(const bf16x8*)&lds[d][1][1][OFS(wn * 64 + 32 + n * 16 + fr, fq)];
    if (i2) SHALF(d, 0, 0, kn2);
    FENCE_BAR();
    __builtin_amdgcn_s_setprio(1);
    #pragma unroll
    for (int m = 0; m < 8; ++m)
      #pragma unroll
      for (int n = 0; n < 2; ++n)
        acc[m][n + 2] = __builtin_amdgcn_mfma_f32_16x16x32_bf16(af[m], bf[n], acc[m][n + 2], 0, 0, 0);
    __builtin_amdgcn_s_setprio(0);
    FENCE_BAR();

    // ---- P4 (kh=1, nh=0): read bf(n0,k1); issue (t+2).B.k0; W2
    #pragma unroll
    for (int n = 0; n < 2; ++n)
      bf[n] = *(const bf16x8*)&lds[d][1][1][OFS(wn * 64 + n * 16 + fr, fq)];
    if (i2) SHALF(d, 1, 0, kn2);
    FENCE_BAR();
    __builtin_amdgcn_s_setprio(1);
    #pragma unroll
    for (int m = 0; m < 8; ++m)
      #pragma unroll
      for (int n = 0; n < 2; ++n)
        acc[m][n] = __builtin_amdgcn_mfma_f32_16x16x32_bf16(af[m], bf[n], acc[m][n], 0, 0, 0);
    __builtin_amdgcn_s_setprio(0);
    if (i1) {
      if (steady) asm volatile("s_waitcnt vmcnt(8)" ::: "memory");
      else        asm volatile("s_waitcnt vmcnt(0)" ::: "memory");
    }
    FENCE_BAR();
  }
  #undef OFS

  // Epilogue: rows rbase..rbase+3 (rbase%4==0) -> one ushort4 at
  // Pz[(rbase>>2)*D_ + t*4].  (identical mapping to gemm1p)
  #pragma unroll
  for (int m = 0; m < 8; ++m)
    #pragma unroll
    for (int n = 0; n < 4; ++n) {
      const int rbase = r0 + wm * 128 + m * 16 + fq * 4;
      const int t = t0 + wn * 64 + n * 16 + fr;
      ushort4 o;
      o.x = f2bf(acc[m][n][0]); o.y = f2bf(acc[m][n][1]);
      o.z = f2bf(acc[m][n][2]); o.w = f2bf(acc[m][n][3]);
      *(ushort4*)&Pz[(size_t)(rbase >> 2) * D_ + t * H_] = o;
    }
}

// ---------------------------------------------------------------------------
// Kernel 1 (pipelined 256x256 2-phase, PROVEN round-6/8): fallback for nz=4.
// ---------------------------------------------------------------------------
__global__ __launch_bounds__(512, 2) void gemm1p_k(
    const unsigned short* __restrict__ Aq,
    const unsigned short* __restrict__ Bq,
    unsigned short* __restrict__ P, int kk_per) {
  __shared__ unsigned short lds[2][2][256 * 64];
  const int r0 = blockIdx.x * 256;
  const int t0 = blockIdx.y * 256;
  const int z  = blockIdx.z;
  const int kbeg = z * kk_per;
  const int NT = kk_per / 64;
  const int tid  = threadIdx.x;
  const int lane = tid & 63, w = tid >> 6;
  const int wm = w >> 2, wn = w & 3;
  const int fr = lane & 15, fq = lane >> 4;
  unsigned short* __restrict__ Pz = P + (size_t)z * MTT_E;

  f32x4 acc[8][4];
  #pragma unroll
  for (int m = 0; m < 8; ++m)
    #pragma unroll
    for (int n = 0; n < 4; ++n) acc[m][n] = (f32x4){0.f, 0.f, 0.f, 0.f};

  auto STAGE = [&](int d, int k0) {
    #pragma unroll
    for (int i = 0; i < 4; ++i) {
      const int q   = (w * 4 + i) * 64 + lane;
      const int row = q >> 3;
      const int c16 = (q & 7) ^ (row & 7);
      __builtin_amdgcn_global_load_lds(
          (const AS1 void*)(Aq + (size_t)(r0 + row) * D_ + k0 + c16 * 8),
          (AS3 void*)(&lds[d][0][(w * 4 + i) * 512]), 16, 0, 0);
    }
    #pragma unroll
    for (int i = 0; i < 4; ++i) {
      const int q   = (w * 4 + i) * 64 + lane;
      const int row = q >> 3;
      const int c16 = (q & 7) ^ (row & 7);
      __builtin_amdgcn_global_load_lds(
          (const AS1 void*)(Bq + (size_t)(t0 + row) * D_ + k0 + c16 * 8),
          (AS3 void*)(&lds[d][1][(w * 4 + i) * 512]), 16, 0, 0);
    }
  };
  #define OFFS(r, c) ((r) * 64 + (((c) ^ ((r) & 7)) * 8))

  STAGE(0, kbeg);

  for (int kt = 0; kt < NT; ++kt) {
    if (kt + 1 < NT) {
      STAGE((kt + 1) & 1, kbeg + (kt + 1) * 64);
      asm volatile("s_waitcnt vmcnt(8)" ::: "memory");
    } else {
      asm volatile("s_waitcnt vmcnt(0)" ::: "memory");
    }
    __builtin_amdgcn_s_barrier();
    __builtin_amdgcn_sched_barrier(0);

    const unsigned short* Ab = &lds[kt & 1][0][0];
    const unsigned short* Bb = &lds[kt & 1][1][0];

    bf16x8 afA[4][2], afB[4][2], bf0[2][2], bf1[2][2];
    #pragma unroll
    for (int m = 0; m < 4; ++m)
      #pragma unroll
      for (int kk = 0; kk < 2; ++kk)
        afA[m][kk] = *(const bf16x8*)&Ab[OFFS(wm * 128 + m * 16 + fr, kk * 4 + fq)];
    #pragma unroll
    for (int n = 0; n < 2; ++n)
      #pragma unroll
      for (int kk = 0; kk < 2; ++kk) {
        bf0[n][kk] = *(const bf16x8*)&Bb[OFFS(wn * 64 + n * 16 + fr, kk * 4 + fq)];
        bf1[n][kk] = *(const bf16x8*)&Bb[OFFS(wn * 64 + 32 + n * 16 + fr, kk * 4 + fq)];
      }

    __builtin_amdgcn_s_setprio(1);
    #pragma unroll
    for (int m = 0; m < 4; ++m)
      #pragma unroll
      for (int n = 0; n < 2; ++n)
        #pragma unroll
        for (int kk = 0; kk < 2; ++kk) {
          acc[m][n]     = __builtin_amdgcn_mfma_f32_16x16x32_bf16(afA[m][kk], bf0[n][kk], acc[m][n], 0, 0, 0);
          acc[m][n + 2] = __builtin_amdgcn_mfma_f32_16x16x32_bf16(afA[m][kk], bf1[n][kk], acc[m][n + 2], 0, 0, 0);
        }
    #pragma unroll
    for (int m = 0; m < 4; ++m)
      #pragma unroll
      for (int kk = 0; kk < 2; ++kk)
        afB[m][kk] = *(const bf16x8*)&Ab[OFFS(wm * 128 + 64 + m * 16 + fr, kk * 4 + fq)];
    #pragma unroll
    for (int m = 0; m < 4; ++m)
      #pragma unroll
      for (int n = 0; n < 2; ++n)
        #pragma unroll
        for (int kk = 0; kk < 2; ++kk) {
          acc[m + 4][n]     = __builtin_amdgcn_mfma_f32_16x16x32_bf16(afB[m][kk], bf0[n][kk], acc[m + 4][n], 0, 0, 0);
          acc[m + 4][n + 2] = __builtin_amdgcn_mfma_f32_16x16x32_bf16(afB[m][kk], bf1[n][kk], acc[m + 4][n + 2], 0, 0, 0);
        }
    __builtin_amdgcn_s_setprio(0);

    __builtin_amdgcn_s_barrier();
    __builtin_amdgcn_sched_barrier(0);
  }
  #undef OFFS

  #pragma unroll
  for (int m = 0; m < 8; ++m)
    #pragma unroll
    for (int n = 0; n < 4; ++n) {
      const int rbase = r0 + wm * 128 + m * 16 + fq * 4;
      const int t = t0 + wn * 64 + n * 16 + fr;
      ushort4 o;
      o.x = f2bf(acc[m][n][0]); o.y = f2bf(acc[m][n][1]);
      o.z = f2bf(acc[m][n][2]); o.w = f2bf(acc[m][n][3]);
      *(ushort4*)&Pz[(size_t)(rbase >> 2) * D_ + t * H_] = o;
    }
}

// ---------------------------------------------------------------------------
// Kernel 1 (m97 structure, proven): used when ws only fits nz<=2.
// ---------------------------------------------------------------------------
__global__ __launch_bounds__(256) void gemm1f_k(
    const unsigned short* __restrict__ Aq,
    const unsigned short* __restrict__ Bq,
    unsigned short* __restrict__ P, int kk) {
  __shared__ unsigned short As[128 * 32];
  __shared__ unsigned short Bs[128 * 32];
  const int r0 = blockIdx.x * 128;
  const int t0 = blockIdx.y * 128;
  const int z  = blockIdx.z;
  const int kbeg = z * kk, kend = kbeg + kk;
  const int tid  = threadIdx.x;
  const int lane = tid & 63, wave = tid >> 6;
  const int wr = wave >> 1, wc = wave & 1;
  const int fr = lane & 15, fq = lane >> 4;
  const int l4 = lane >> 2, lb = lane & 3;
  unsigned short* __restrict__ Pz = P + (size_t)z * MTT_E;

  f32x4 acc[4][4];
  #pragma unroll
  for (int m = 0; m < 4; ++m)
    #pragma unroll
    for (int n = 0; n < 4; ++n) acc[m][n] = (f32x4){0.f, 0.f, 0.f, 0.f};

  for (int k0 = kbeg; k0 < kend; k0 += 32) {
    __syncthreads();
    #pragma unroll
    for (int c = 0; c < 2; ++c) {
      const int ch  = wave * 2 + c;
      const int row = ch * 16 + l4;
      __builtin_amdgcn_global_load_lds(
          (const AS1 void*)(Aq + (size_t)(r0 + row) * D_ + k0 + lb * 8),
          (AS3 void*)(As + ch * 512), 16, 0, 0);
      __builtin_amdgcn_global_load_lds(
          (const AS1 void*)(Bq + (size_t)(t0 + row) * D_ + k0 + lb * 8),
          (AS3 void*)(Bs + ch * 512), 16, 0, 0);
    }
    __syncthreads();
    bf16x8 af[4], bf[4];
    #pragma unroll
    for (int m = 0; m < 4; ++m)
      af[m] = *(const bf16x8*)&As[(wr * 64 + m * 16 + fr) * 32 + fq * 8];
    #pragma unroll
    for (int n = 0; n < 4; ++n)
      bf[n] = *(const bf16x8*)&Bs[(wc * 64 + n * 16 + fr) * 32 + fq * 8];
    #pragma unroll
    for (int m = 0; m < 4; ++m)
      #pragma unroll
      for (int n = 0; n < 4; ++n)
        acc[m][n] = __builtin_amdgcn_mfma_f32_16x16x32_bf16(af[m], bf[n], acc[m][n], 0, 0, 0);
  }
  #pragma unroll
  for (int m = 0; m < 4; ++m)
    #pragma unroll
    for (int n = 0; n < 4; ++n) {
      const int rbase = r0 + wr * 64 + m * 16 + fq * 4;
      const int t = t0 + wc * 64 + n * 16 + fr;
      ushort4 o;
      o.x = f2bf(acc[m][n][0]); o.y = f2bf(acc[m][n][1]);
      o.z = f2bf(acc[m][n][2]); o.w = f2bf(acc[m][n][3]);
      *(ushort4*)&Pz[(size_t)(rbase >> 2) * D_ + t * H_] = o;
    }
}

// ---------------------------------------------------------------------------
// Fused reduce+gather, LDS-staged (proven round-8).
// ---------------------------------------------------------------------------
__global__ __launch_bounds__(256) void rgather_k(
    const unsigned short* __restrict__ P, const int* __restrict__ x,
    unsigned short* __restrict__ GT, int nz) {
  __shared__ int toks[B_ * T_];          // 16 KB
  __shared__ unsigned short row[D_];     // 16 KB
  const int tid = threadIdx.x;
  #pragma unroll
  for (int c = 0; c < 16; ++c) toks[c * 256 + tid] = x[c * 256 + tid];

  const int e = blockIdx.x;
  const unsigned short* prow = P + (size_t)e * D_;

  float s[8][4];
  #pragma unroll
  for (int i = 0; i < 8; ++i) { s[i][0] = s[i][1] = s[i][2] = s[i][3] = 0.f; }
  for (int z = 0; z < nz; ++z) {
    const unsigned short* pz = prow + (size_t)z * MTT_E;
    #pragma unroll
    for (int i = 0; i < 8; ++i) {
      const ushort4 v = *(const ushort4*)(pz + (size_t)(i * 256 + tid) * 4);
      s[i][0] += bf2f(v.x); s[i][1] += bf2f(v.y);
      s[i][2] += bf2f(v.z); s[i][3] += bf2f(v.w);
    }
  }
  #pragma unroll
  for (int i = 0; i < 8; ++i) {
    ushort4 o;
    o.x = f2bf(s[i][0]); o.y = f2bf(s[i][1]);
    o.z = f2bf(s[i][2]); o.w = f2bf(s[i][3]);
    *(ushort4*)&row[(i * 256 + tid) * 4] = o;
  }
  __syncthreads();

  const int lane = tid & 63, wave = tid >> 6;
  #pragma unroll
  for (int bb = 0; bb < 2; ++bb) {
    const int b = wave * 2 + bb;
    unsigned short* grow = GT + ((size_t)b * NE_ + e) * K3;
    const int* tb = toks + b * T_;
    #pragma unroll
    for (int r = 0; r < 8; ++r) {
      const int j = r * 64 + lane;
      const uint2 v = *(const uint2*)&row[tb[j] * H_];
      *(uint2*)(grow + j * H_) = v;
    }
  }
}

// ---------------------------------------------------------------------------
// Kernel 3 (dense): y[b][i][e] = sum_k att[b,i,k] * GT[b,e,k] + pb[e]
// ---------------------------------------------------------------------------
__global__ __launch_bounds__(256) void gemm3f_k(
    const unsigned short* __restrict__ att,
    const unsigned short* __restrict__ GT,
    const float* __restrict__ bias,
    float* __restrict__ y) {
  __shared__ unsigned short As[128 * 32];
  __shared__ unsigned short Bs[64 * 32];
  const int b  = blockIdx.z;
  const int i0 = blockIdx.x * 128;
  const int e0 = blockIdx.y * 64;
  const int tid  = threadIdx.x;
  const int lane = tid & 63, wave = tid >> 6;
  const int wr = wave >> 1, wc = wave & 1;
  const int fr = lane & 15, fq = lane >> 4;

  f32x4 acc[4][2];
  #pragma unroll
  for (int m = 0; m < 4; ++m)
    #pragma unroll
    for (int n = 0; n < 2; ++n) acc[m][n] = (f32x4){0.f, 0.f, 0.f, 0.f};

  const unsigned short* aB = att + (size_t)(b * T_ + i0) * K3;
  const unsigned short* bB = GT + ((size_t)b * NE_ + e0) * K3;

  for (int k0 = 0; k0 < K3; k0 += 32) {
    __syncthreads();
    #pragma unroll
    for (int rdi = 0; rdi < 2; ++rdi) {
      const int q = rdi * 256 + tid;
      const int row = q >> 2, koff = (q & 3) * 8;
      __builtin_amdgcn_global_load_lds(
          (const AS1 void*)(aB + (size_t)row * K3 + k0 + koff),
          (AS3 void*)(As + q * 8), 16, 0, 0);
    }
    {
      const int q = tid;
      const int row = q >> 2, koff = (q & 3) * 8;
      __builtin_amdgcn_global_load_lds(
          (const AS1 void*)(bB + (size_t)row * K3 + k0 + koff),
          (AS3 void*)(Bs + q * 8), 16, 0, 0);
    }
    __syncthreads();
    bf16x8 af[4], bf[2];
    #pragma unroll
    for (int m = 0; m < 4; ++m)
      af[m] = *(const bf16x8*)&As[(wr * 64 + m * 16 + fr) * 32 + fq * 8];
    #pragma unroll
    for (int n = 0; n < 2; ++n)
      bf[n] = *(const bf16x8*)&Bs[(wc * 32 + n * 16 + fr) * 32 + fq * 8];
    #pragma unroll
    for (int m = 0; m < 4; ++m)
      #pragma unroll
      for (int n = 0; n < 2; ++n)
        acc[m][n] = __builtin_amdgcn_mfma_f32_16x16x32_bf16(af[m], bf[n], acc[m][n], 0, 0, 0);
  }

  #pragma unroll
  for (int m = 0; m < 4; ++m)
    #pragma unroll
    for (int n = 0; n < 2; ++n) {
      const int i = i0 + wr * 64 + m * 16 + fq * 4;
      const int e = e0 + wc * 32 + n * 16 + fr;
      const float be = bias[e];
      #pragma unroll
      for (int g = 0; g < 4; ++g)
        y[(size_t)(b * T_ + i + g) * NE_ + e] = acc[m][n][g] + be;
    }
}

// ---------------------------------------------------------------------------
// Kernel 2: att[b][i][j*4+h] = softmax_j(cooc[t_i, t_j, h]) + eye  (bf16)
// ---------------------------------------------------------------------------
__global__ __launch_bounds__(64) void softmax_k(
    const int* __restrict__ x, const float* __restrict__ cooc,
    unsigned short* __restrict__ att) {
  const int bi = blockIdx.x;
  const int b = bi >> 9, i = bi & (T_ - 1);
  const int lane = threadIdx.x;
  const int ti = x[b * T_ + i];
  const float* crow = cooc + (size_t)ti * D_;

  float w[8][4];
  #pragma unroll
  for (int r = 0; r < 8; ++r) {
    const int j = lane + r * 64;
    const int tj = x[b * T_ + j];
    const float4 v = *(const float4*)(crow + (size_t)tj * H_);
    w[r][0] = v.x; w[r][1] = v.y; w[r][2] = v.z; w[r][3] = v.w;
  }
  float m[4] = {-1e30f, -1e30f, -1e30f, -1e30f};
  #pragma unroll
  for (int r = 0; r < 8; ++r)
    #pragma unroll
    for (int h = 0; h < 4; ++h) m[h] = fmaxf(m[h], w[r][h]);
  #pragma unroll
  for (int off = 32; off > 0; off >>= 1)
    #pragma unroll
    for (int h = 0; h < 4; ++h) m[h] = fmaxf(m[h], __shfl_xor(m[h], off));
  float s[4] = {0.f, 0.f, 0.f, 0.f};
  #pragma unroll
  for (int r = 0; r < 8; ++r)
    #pragma unroll
    for (int h = 0; h < 4; ++h) { w[r][h] = __expf(w[r][h] - m[h]); s[h] += w[r][h]; }
  #pragma unroll
  for (int off = 32; off > 0; off >>= 1)
    #pragma unroll
    for (int h = 0; h < 4; ++h) s[h] += __shfl_xor(s[h], off);
  float inv[4];
  #pragma unroll
  for (int h = 0; h < 4; ++h) inv[h] = 1.f / s[h];

  unsigned short* arow = att + (size_t)(b * T_ + i) * (T_ * H_);
  #pragma unroll
  for (int r = 0; r < 8; ++r) {
    const int j = lane + r * 64;
    const float d = (j == i) ? 1.f : 0.f;
    ushort4 o;
    o.x = f2bf(w[r][0] * inv[0] + d);
    o.y = f2bf(w[r][1] * inv[1] + d);
    o.z = f2bf(w[r][2] * inv[2] + d);
    o.w = f2bf(w[r][3] * inv[3] + d);
    *(ushort4*)(arow + (size_t)j * H_) = o;
  }
}

// ---------------------------------------------------------------------------
// Round-1 fallback kernels (tiny ws)
// ---------------------------------------------------------------------------
__global__ __launch_bounds__(256) void gemm1_k(
    const float* __restrict__ pw, const float* __restrict__ cooc,
    unsigned short* __restrict__ mtT) {
  __shared__ unsigned short As[128 * 32];
  __shared__ unsigned short Bs[64 * 32];
  const int h  = blockIdx.z;
  const int e0 = blockIdx.x * 128;
  const int t0 = blockIdx.y * 64;
  const int tid  = threadIdx.x;
  const int lane = tid & 63, wave = tid >> 6;
  const int wr = wave >> 1, wc = wave & 1;
  const int fr = lane & 15, fq = lane >> 4;

  f32x4 acc[4][2];
  #pragma unroll
  for (int m = 0; m < 4; ++m)
    #pragma unroll
    for (int n = 0; n < 2; ++n) acc[m][n] = (f32x4){0.f, 0.f, 0.f, 0.f};

  const float* aB = pw + (size_t)e0 * PWROW + (size_t)h * D_;
  const float* bB = cooc + (size_t)t0 * D_;

  for (int k0 = 0; k0 < D_; k0 += 32) {
    __syncthreads();
    #pragma unroll
    for (int c = 0; c < 4; ++c) {
      const int fe = (c * 256 + tid) * 4;
      const int row = fe >> 5, k = fe & 31;
      const float4 v = *(const float4*)(aB + (size_t)row * PWROW + k0 + k);
      ushort4 o; o.x = f2bf(v.x); o.y = f2bf(v.y); o.z = f2bf(v.z); o.w = f2bf(v.w);
      *(ushort4*)&As[fe] = o;
    }
    #pragma unroll
    for (int c = 0; c < 2; ++c) {
      const int fe = (c * 256 + tid) * 4;
      const int row = fe >> 5, k = fe & 31;
      const float4 v = *(const float4*)(bB + (size_t)row * D_ + k0 + k);
      ushort4 o; o.x = f2bf(v.x); o.y = f2bf(v.y); o.z = f2bf(v.z); o.w = f2bf(v.w);
      *(ushort4*)&Bs[fe] = o;
    }
    __syncthreads();
    bf16x8 af[4], bf[2];
    #pragma unroll
    for (int m = 0; m < 4; ++m)
      af[m] = *(const bf16x8*)&As[(wr * 64 + m * 16 + fr) * 32 + fq * 8];
    #pragma unroll
    for (int n = 0; n < 2; ++n)
      bf[n] = *(const bf16x8*)&Bs[(wc * 32 + n * 16 + fr) * 32 + fq * 8];
    #pragma unroll
    for (int m = 0; m < 4; ++m)
      #pragma unroll
      for (int n = 0; n < 2; ++n)
        acc[m][n] = __builtin_amdgcn_mfma_f32_16x16x32_bf16(af[m], bf[n], acc[m][n], 0, 0, 0);
  }
  #pragma unroll
  for (int m = 0; m < 4; ++m)
    #pragma unroll
    for (int n = 0; n < 2; ++n) {
      const int e = e0 + wr * 64 + m * 16 + fq * 4;
      const int t = t0 + wc * 32 + n * 16 + fr;
      #pragma unroll
      for (int g = 0; g < 4; ++g)
        mtT[(size_t)(e + g) * D_ + t * H_ + h] = f2bf(acc[m][n][g]);
    }
}

__global__ __launch_bounds__(256) void gemm3_k(
    const unsigned short* __restrict__ att, const unsigned short* __restrict__ mtT,
    const int* __restrict__ x, const float* __restrict__ bias,
    float* __restrict__ y) {
  __shared__ unsigned short As[64 * 32];
  __shared__ unsigned short Bs[128 * 32];
  const int b  = blockIdx.z;
  const int i0 = blockIdx.x * 64;
  const int e0 = blockIdx.y * 128;
  const int tid  = threadIdx.x;
  const int lane = tid & 63, wave = tid >> 6;
  const int wr = wave >> 1, wc = wave & 1;
  const int fr = lane & 15, fq = lane >> 4;

  f32x4 acc[2][4];
  #pragma unroll
  for (int m = 0; m < 2; ++m)
    #pragma unroll
    for (int n = 0; n < 4; ++n) acc[m][n] = (f32x4){0.f, 0.f, 0.f, 0.f};

  const unsigned short* aB = att + (size_t)(b * T_ + i0) * (T_ * H_);

  for (int ks = 0; ks < 64; ++ks) {
    const int k0 = ks * 32;
    __syncthreads();
    {
      const int fe = tid * 8;
      const int row = fe >> 5, k = fe & 31;
      const uint4 v = *(const uint4*)(aB + (size_t)row * (T_ * H_) + k0 + k);
      *(uint4*)&As[fe] = v;
    }
    #pragma unroll
    for (int c = 0; c < 4; ++c) {
      const int q = c * 256 + tid;
      const int n = q >> 3, j8 = q & 7;
      const int tj = x[b * T_ + ks * 8 + j8];
      const uint2 v = *(const uint2*)(mtT + (size_t)(e0 + n) * D_ + tj * H_);
      *(uint2*)&Bs[n * 32 + j8 * 4] = v;
    }
    __syncthreads();
    bf16x8 af[2], bf[4];
    #pragma unroll
    for (int m = 0; m < 2; ++m)
      af[m] = *(const bf16x8*)&As[(wr * 32 + m * 16 + fr) * 32 + fq * 8];
    #pragma unroll
    for (int n = 0; n < 4; ++n)
      bf[n] = *(const bf16x8*)&Bs[(wc * 64 + n * 16 + fr) * 32 + fq * 8];
    #pragma unroll
    for (int m = 0; m < 2; ++m)
      #pragma unroll
      for (int n = 0; n < 4; ++n)
        acc[m][n] = __builtin_amdgcn_mfma_f32_16x16x32_bf16(af[m], bf[n], acc[m][n], 0, 0, 0);
  }
  #pragma unroll
  for (int m = 0; m < 2; ++m)
    #pragma unroll
    for (int n = 0; n < 4; ++n) {
      const int i = i0 + wr * 32 + m * 16 + fq * 4;
      const int e = e0 + wc * 64 + n * 16 + fr;
      const float be = bias[e];
      #pragma unroll
      for (int g = 0; g < 4; ++g)
        y[(size_t)(b * T_ + i + g) * NE_ + e] = acc[m][n][g] + be;
    }
}

// ---------------------------------------------------------------------------
extern "C" void kernel_launch(void* const* d_in, const int* in_sizes, int n_in,
                              void* d_out, int out_size, void* d_ws, size_t ws_size,
                              hipStream_t stream) {
  const int*   x    = (const int*)d_in[0];
  const float* cooc = (const float*)d_in[1];
  const float* pw   = (const float*)d_in[2];
  const float* pb   = (const float*)d_in[3];
  float* y = (float*)d_out;

  const size_t BQ_E = (size_t)V_ * D_;           // 16777216
  const size_t AQ_E = (size_t)M1 * D_;           // 25165824

  unsigned short* mtT = (unsigned short*)d_ws;   // == P0
  auto need = [&](int c) { return ((size_t)c * MTT_E + BQ_E + AQ_E) * 2; };

  int nz = 0;
  if      (ws_size >= need(8)) nz = 8;   // 8-phase gemm1e (768 blocks)
  else if (ws_size >= need(4)) nz = 4;   // proven gemm1p
  else if (ws_size >= need(2)) nz = 2;   // gemm1f
  else if (ws_size >= need(1)) nz = 1;

  if (nz >= 1) {
    unsigned short* Bq  = mtT + (size_t)nz * MTT_E;
    unsigned short* Aq  = Bq + BQ_E;
    unsigned short* GT  = Bq;   // alias: valid after gemm1
    unsigned short* att = Aq;   // alias: valid after gemm1
    hipLaunchKernelGGL(cvtAB_k, dim3(2048), dim3(256), 0, stream,
                       cooc, pw, Bq, (int)(BQ_E / 4), (int)((BQ_E + AQ_E) / 4));
    if (nz == 8)
      hipLaunchKernelGGL(gemm1e_k, dim3(M1 / 256, V_ / 256, 8), dim3(512), 0,
                         stream, Aq, Bq, mtT, D_ / 8);
    else if (nz == 4)
      hipLaunchKernelGGL(gemm1p_k, dim3(M1 / 256, V_ / 256, 4), dim3(512), 0,
                         stream, Aq, Bq, mtT, D_ / 4);
    else
      hipLaunchKernelGGL(gemm1f_k, dim3(M1 / 128, V_ / 128, nz), dim3(256), 0,
                         stream, Aq, Bq, mtT, D_ / nz);
    hipLaunchKernelGGL(softmax_k, dim3(B_ * T_), dim3(64), 0, stream, x, cooc, att);
    hipLaunchKernelGGL(rgather_k, dim3(NE_), dim3(256), 0, stream, mtT, x, GT, nz);
    hipLaunchKernelGGL(gemm3f_k, dim3(T_ / 128, NE_ / 64, B_), dim3(256), 0, stream,
                       att, GT, pb, y);
  } else {
    unsigned short* att = mtT + MTT_E;
    hipLaunchKernelGGL(gemm1_k, dim3(NE_ / 128, V_ / 64, H_), dim3(256), 0, stream,
                       pw, cooc, mtT);
    hipLaunchKernelGGL(softmax_k, dim3(B_ * T_), dim3(64), 0, stream, x, cooc, att);
    hipLaunchKernelGGL(gemm3_k, dim3(T_ / 64, NE_ / 128, B_), dim3(256), 0, stream,
                       att, mtT, x, pb, y);
  }
}

// Round 13
// 232.954 us; speedup vs baseline: 1.0022x; 1.0022x over previous
//
#include <hip/hip_runtime.h>
#include <stdint.h>

// Problem constants
#define B_    8
#define T_    512
#define V_    2048
#define H_    4
#define NE_   768
#define D_    8192      // V_*H_
#define PWROW 32768     // V_*H_*H_
#define M1    3072      // NE_*H_
#define K3    2048      // T_*H_
#define MTT_E 6291456UL // NE_*D_

#define AS1 __attribute__((address_space(1)))
#define AS3 __attribute__((address_space(3)))

typedef __attribute__((ext_vector_type(8))) short bf16x8;
typedef __attribute__((ext_vector_type(4))) float f32x4;

__device__ __forceinline__ unsigned short f2bf(float f) {
  union { float f; unsigned int u; } c; c.f = f;
  unsigned int u = c.u;
  return (unsigned short)((u + 0x7FFFu + ((u >> 16) & 1u)) >> 16);
}
__device__ __forceinline__ float bf2f(unsigned short s) {
  union { unsigned int u; float f; } c; c.u = ((unsigned int)s) << 16;
  return c.f;
}

// ---------------------------------------------------------------------------
// fp32 -> bf16 convert of BOTH inputs in one launch.
// dst layout: [Bq (from cooc)][Aq (from pw)] contiguous.
// ---------------------------------------------------------------------------
__global__ __launch_bounds__(256) void cvtAB_k(
    const float* __restrict__ cooc, const float* __restrict__ pw,
    unsigned short* __restrict__ dst, int bq4, int n4) {
  int i = blockIdx.x * 256 + threadIdx.x;
  const int stride = gridDim.x * 256;
  for (; i < n4; i += stride) {
    const float4 v = (i < bq4) ? ((const float4*)cooc)[i]
                               : ((const float4*)pw)[i - bq4];
    ushort4 o;
    o.x = f2bf(v.x); o.y = f2bf(v.y); o.z = f2bf(v.z); o.w = f2bf(v.w);
    ((ushort4*)dst)[i] = o;
  }
}

// ---------------------------------------------------------------------------
// Kernel 1 (pipelined 256x256 2-phase, PROVEN round-6/8 @114us): C[m][t]
// over K-slice z. 8 waves (2M x 4N), BK=64, 128KB LDS double-buffer,
// global_load_lds 16B staging, counted vmcnt(8) (loads span barriers),
// chunk-XOR swizzle on both sides, setprio around MFMA.
// NOTE (r12 model): this kernel is LDS-BW-bound (192KB LDS reads/tile ~=
// MFMA cycles); 4 schedule variants all land 114-134us -> structural floor.
// Register note (r9): acc=128 AGPR + ~112 VGPR is at the 2-waves/SIMD cap;
// do NOT add reg-staged operands (spills -> 3.4x).
// Output: partial z in mtT scatter layout [e][t*4+h], bf16 ushort4 stores.
// ---------------------------------------------------------------------------
__global__ __launch_bounds__(512, 2) void gemm1p_k(
    const unsigned short* __restrict__ Aq,   // [3072][8192]
    const unsigned short* __restrict__ Bq,   // [2048][8192]
    unsigned short* __restrict__ P,          // partials, z-strided by MTT_E
    int kk_per) {
  __shared__ unsigned short lds[2][2][256 * 64];   // [dbuf][A=0/B=1] 128 KB
  const int r0 = blockIdx.x * 256;   // m
  const int t0 = blockIdx.y * 256;   // t
  const int z  = blockIdx.z;
  const int kbeg = z * kk_per;
  const int NT = kk_per / 64;
  const int tid  = threadIdx.x;
  const int lane = tid & 63, w = tid >> 6;
  const int wm = w >> 2, wn = w & 3;
  const int fr = lane & 15, fq = lane >> 4;
  unsigned short* __restrict__ Pz = P + (size_t)z * MTT_E;

  f32x4 acc[8][4];
  #pragma unroll
  for (int m = 0; m < 8; ++m)
    #pragma unroll
    for (int n = 0; n < 4; ++n) acc[m][n] = (f32x4){0.f, 0.f, 0.f, 0.f};

  auto STAGE = [&](int d, int k0) {
    #pragma unroll
    for (int i = 0; i < 4; ++i) {
      const int q   = (w * 4 + i) * 64 + lane;
      const int row = q >> 3;
      const int c16 = (q & 7) ^ (row & 7);
      __builtin_amdgcn_global_load_lds(
          (const AS1 void*)(Aq + (size_t)(r0 + row) * D_ + k0 + c16 * 8),
          (AS3 void*)(&lds[d][0][(w * 4 + i) * 512]), 16, 0, 0);
    }
    #pragma unroll
    for (int i = 0; i < 4; ++i) {
      const int q   = (w * 4 + i) * 64 + lane;
      const int row = q >> 3;
      const int c16 = (q & 7) ^ (row & 7);
      __builtin_amdgcn_global_load_lds(
          (const AS1 void*)(Bq + (size_t)(t0 + row) * D_ + k0 + c16 * 8),
          (AS3 void*)(&lds[d][1][(w * 4 + i) * 512]), 16, 0, 0);
    }
  };
  #define OFFS(r, c) ((r) * 64 + (((c) ^ ((r) & 7)) * 8))

  STAGE(0, kbeg);

  for (int kt = 0; kt < NT; ++kt) {
    if (kt + 1 < NT) {
      STAGE((kt + 1) & 1, kbeg + (kt + 1) * 64);
      asm volatile("s_waitcnt vmcnt(8)" ::: "memory");   // stage(kt) landed
    } else {
      asm volatile("s_waitcnt vmcnt(0)" ::: "memory");
    }
    __builtin_amdgcn_s_barrier();
    __builtin_amdgcn_sched_barrier(0);

    const unsigned short* Ab = &lds[kt & 1][0][0];
    const unsigned short* Bb = &lds[kt & 1][1][0];

    bf16x8 afA[4][2], afB[4][2], bf0[2][2], bf1[2][2];
    #pragma unroll
    for (int m = 0; m < 4; ++m)
      #pragma unroll
      for (int kk = 0; kk < 2; ++kk)
        afA[m][kk] = *(const bf16x8*)&Ab[OFFS(wm * 128 + m * 16 + fr, kk * 4 + fq)];
    #pragma unroll
    for (int n = 0; n < 2; ++n)
      #pragma unroll
      for (int kk = 0; kk < 2; ++kk) {
        bf0[n][kk] = *(const bf16x8*)&Bb[OFFS(wn * 64 + n * 16 + fr, kk * 4 + fq)];
        bf1[n][kk] = *(const bf16x8*)&Bb[OFFS(wn * 64 + 32 + n * 16 + fr, kk * 4 + fq)];
      }

    __builtin_amdgcn_s_setprio(1);
    #pragma unroll
    for (int m = 0; m < 4; ++m)
      #pragma unroll
      for (int n = 0; n < 2; ++n)
        #pragma unroll
        for (int kk = 0; kk < 2; ++kk) {
          acc[m][n]     = __builtin_amdgcn_mfma_f32_16x16x32_bf16(afA[m][kk], bf0[n][kk], acc[m][n], 0, 0, 0);
          acc[m][n + 2] = __builtin_amdgcn_mfma_f32_16x16x32_bf16(afA[m][kk], bf1[n][kk], acc[m][n + 2], 0, 0, 0);
        }
    #pragma unroll
    for (int m = 0; m < 4; ++m)
      #pragma unroll
      for (int kk = 0; kk < 2; ++kk)
        afB[m][kk] = *(const bf16x8*)&Ab[OFFS(wm * 128 + 64 + m * 16 + fr, kk * 4 + fq)];
    #pragma unroll
    for (int m = 0; m < 4; ++m)
      #pragma unroll
      for (int n = 0; n < 2; ++n)
        #pragma unroll
        for (int kk = 0; kk < 2; ++kk) {
          acc[m + 4][n]     = __builtin_amdgcn_mfma_f32_16x16x32_bf16(afB[m][kk], bf0[n][kk], acc[m + 4][n], 0, 0, 0);
          acc[m + 4][n + 2] = __builtin_amdgcn_mfma_f32_16x16x32_bf16(afB[m][kk], bf1[n][kk], acc[m + 4][n + 2], 0, 0, 0);
        }
    __builtin_amdgcn_s_setprio(0);

    __builtin_amdgcn_s_barrier();
    __builtin_amdgcn_sched_barrier(0);
  }
  #undef OFFS

  #pragma unroll
  for (int m = 0; m < 8; ++m)
    #pragma unroll
    for (int n = 0; n < 4; ++n) {
      const int rbase = r0 + wm * 128 + m * 16 + fq * 4;
      const int t = t0 + wn * 64 + n * 16 + fr;
      ushort4 o;
      o.x = f2bf(acc[m][n][0]); o.y = f2bf(acc[m][n][1]);
      o.z = f2bf(acc[m][n][2]); o.w = f2bf(acc[m][n][3]);
      *(ushort4*)&Pz[(size_t)(rbase >> 2) * D_ + t * H_] = o;
    }
}

// ---------------------------------------------------------------------------
// Kernel 1 (m97 structure, proven): used when ws only fits nz<=2.
// ---------------------------------------------------------------------------
__global__ __launch_bounds__(256) void gemm1f_k(
    const unsigned short* __restrict__ Aq,
    const unsigned short* __restrict__ Bq,
    unsigned short* __restrict__ P, int kk) {
  __shared__ unsigned short As[128 * 32];
  __shared__ unsigned short Bs[128 * 32];
  const int r0 = blockIdx.x * 128;
  const int t0 = blockIdx.y * 128;
  const int z  = blockIdx.z;
  const int kbeg = z * kk, kend = kbeg + kk;
  const int tid  = threadIdx.x;
  const int lane = tid & 63, wave = tid >> 6;
  const int wr = wave >> 1, wc = wave & 1;
  const int fr = lane & 15, fq = lane >> 4;
  const int l4 = lane >> 2, lb = lane & 3;
  unsigned short* __restrict__ Pz = P + (size_t)z * MTT_E;

  f32x4 acc[4][4];
  #pragma unroll
  for (int m = 0; m < 4; ++m)
    #pragma unroll
    for (int n = 0; n < 4; ++n) acc[m][n] = (f32x4){0.f, 0.f, 0.f, 0.f};

  for (int k0 = kbeg; k0 < kend; k0 += 32) {
    __syncthreads();
    #pragma unroll
    for (int c = 0; c < 2; ++c) {
      const int ch  = wave * 2 + c;
      const int row = ch * 16 + l4;
      __builtin_amdgcn_global_load_lds(
          (const AS1 void*)(Aq + (size_t)(r0 + row) * D_ + k0 + lb * 8),
          (AS3 void*)(As + ch * 512), 16, 0, 0);
      __builtin_amdgcn_global_load_lds(
          (const AS1 void*)(Bq + (size_t)(t0 + row) * D_ + k0 + lb * 8),
          (AS3 void*)(Bs + ch * 512), 16, 0, 0);
    }
    __syncthreads();
    bf16x8 af[4], bf[4];
    #pragma unroll
    for (int m = 0; m < 4; ++m)
      af[m] = *(const bf16x8*)&As[(wr * 64 + m * 16 + fr) * 32 + fq * 8];
    #pragma unroll
    for (int n = 0; n < 4; ++n)
      bf[n] = *(const bf16x8*)&Bs[(wc * 64 + n * 16 + fr) * 32 + fq * 8];
    #pragma unroll
    for (int m = 0; m < 4; ++m)
      #pragma unroll
      for (int n = 0; n < 4; ++n)
        acc[m][n] = __builtin_amdgcn_mfma_f32_16x16x32_bf16(af[m], bf[n], acc[m][n], 0, 0, 0);
  }
  #pragma unroll
  for (int m = 0; m < 4; ++m)
    #pragma unroll
    for (int n = 0; n < 4; ++n) {
      const int rbase = r0 + wr * 64 + m * 16 + fq * 4;
      const int t = t0 + wc * 64 + n * 16 + fr;
      ushort4 o;
      o.x = f2bf(acc[m][n][0]); o.y = f2bf(acc[m][n][1]);
      o.z = f2bf(acc[m][n][2]); o.w = f2bf(acc[m][n][3]);
      *(ushort4*)&Pz[(size_t)(rbase >> 2) * D_ + t * H_] = o;
    }
}

// ---------------------------------------------------------------------------
// Fused reduce+gather, LDS-staged (proven round-8).
// ---------------------------------------------------------------------------
__global__ __launch_bounds__(256) void rgather_k(
    const unsigned short* __restrict__ P, const int* __restrict__ x,
    unsigned short* __restrict__ GT, int nz) {
  __shared__ int toks[B_ * T_];          // 16 KB
  __shared__ unsigned short row[D_];     // 16 KB
  const int tid = threadIdx.x;
  #pragma unroll
  for (int c = 0; c < 16; ++c) toks[c * 256 + tid] = x[c * 256 + tid];

  const int e = blockIdx.x;
  const unsigned short* prow = P + (size_t)e * D_;

  float s[8][4];
  #pragma unroll
  for (int i = 0; i < 8; ++i) { s[i][0] = s[i][1] = s[i][2] = s[i][3] = 0.f; }
  for (int z = 0; z < nz; ++z) {
    const unsigned short* pz = prow + (size_t)z * MTT_E;
    #pragma unroll
    for (int i = 0; i < 8; ++i) {
      const ushort4 v = *(const ushort4*)(pz + (size_t)(i * 256 + tid) * 4);
      s[i][0] += bf2f(v.x); s[i][1] += bf2f(v.y);
      s[i][2] += bf2f(v.z); s[i][3] += bf2f(v.w);
    }
  }
  #pragma unroll
  for (int i = 0; i < 8; ++i) {
    ushort4 o;
    o.x = f2bf(s[i][0]); o.y = f2bf(s[i][1]);
    o.z = f2bf(s[i][2]); o.w = f2bf(s[i][3]);
    *(ushort4*)&row[(i * 256 + tid) * 4] = o;
  }
  __syncthreads();

  const int lane = tid & 63, wave = tid >> 6;
  #pragma unroll
  for (int bb = 0; bb < 2; ++bb) {
    const int b = wave * 2 + bb;
    unsigned short* grow = GT + ((size_t)b * NE_ + e) * K3;
    const int* tb = toks + b * T_;
    #pragma unroll
    for (int r = 0; r < 8; ++r) {
      const int j = r * 64 + lane;
      const uint2 v = *(const uint2*)&row[tb[j] * H_];
      *(uint2*)(grow + j * H_) = v;
    }
  }
}

// ---------------------------------------------------------------------------
// Kernel 3 (NEW: dbuf + counted vmcnt): y[b][i][e] = sum_k att*GT + pb.
// Same BM=128/BN=64/BK=32 tiles and bank-free LDS layout as the proven
// gemm3f, but double-buffered with vmcnt(3) (next tile's 3 loads stay in
// flight across the barrier) + raw s_barrier + setprio — the gemm1p
// mechanism. 24KB LDS -> ~6 blocks/CU.
// ---------------------------------------------------------------------------
__global__ __launch_bounds__(256) void gemm3d_k(
    const unsigned short* __restrict__ att,  // [B*T][2048]
    const unsigned short* __restrict__ GT,   // [B][768][2048]
    const float* __restrict__ bias,
    float* __restrict__ y) {
  __shared__ unsigned short As[2][128 * 32];
  __shared__ unsigned short Bs[2][64 * 32];
  const int b  = blockIdx.z;
  const int i0 = blockIdx.x * 128;
  const int e0 = blockIdx.y * 64;
  const int tid  = threadIdx.x;
  const int lane = tid & 63, wave = tid >> 6;
  const int wr = wave >> 1, wc = wave & 1;
  const int fr = lane & 15, fq = lane >> 4;

  f32x4 acc[4][2];
  #pragma unroll
  for (int m = 0; m < 4; ++m)
    #pragma unroll
    for (int n = 0; n < 2; ++n) acc[m][n] = (f32x4){0.f, 0.f, 0.f, 0.f};

  const unsigned short* aB = att + (size_t)(b * T_ + i0) * K3;
  const unsigned short* bB = GT + ((size_t)b * NE_ + e0) * K3;

  auto STAGE = [&](int d, int k0) {
    #pragma unroll
    for (int rdi = 0; rdi < 2; ++rdi) {
      const int q = rdi * 256 + tid;
      const int row = q >> 2, koff = (q & 3) * 8;
      __builtin_amdgcn_global_load_lds(
          (const AS1 void*)(aB + (size_t)row * K3 + k0 + koff),
          (AS3 void*)(&As[d][q * 8]), 16, 0, 0);
    }
    {
      const int q = tid;
      const int row = q >> 2, koff = (q & 3) * 8;
      __builtin_amdgcn_global_load_lds(
          (const AS1 void*)(bB + (size_t)row * K3 + k0 + koff),
          (AS3 void*)(&Bs[d][q * 8]), 16, 0, 0);
    }
  };

  STAGE(0, 0);

  for (int kt = 0; kt < 64; ++kt) {
    if (kt + 1 < 64) {
      STAGE((kt + 1) & 1, (kt + 1) * 32);
      asm volatile("s_waitcnt vmcnt(3)" ::: "memory");   // tile kt landed
    } else {
      asm volatile("s_waitcnt vmcnt(0)" ::: "memory");
    }
    __builtin_amdgcn_s_barrier();
    __builtin_amdgcn_sched_barrier(0);

    const unsigned short* Ab = &As[kt & 1][0];
    const unsigned short* Bb = &Bs[kt & 1][0];
    bf16x8 af[4], bf[2];
    #pragma unroll
    for (int m = 0; m < 4; ++m)
      af[m] = *(const bf16x8*)&Ab[(wr * 64 + m * 16 + fr) * 32 + fq * 8];
    #pragma unroll
    for (int n = 0; n < 2; ++n)
      bf[n] = *(const bf16x8*)&Bb[(wc * 32 + n * 16 + fr) * 32 + fq * 8];

    __builtin_amdgcn_s_setprio(1);
    #pragma unroll
    for (int m = 0; m < 4; ++m)
      #pragma unroll
      for (int n = 0; n < 2; ++n)
        acc[m][n] = __builtin_amdgcn_mfma_f32_16x16x32_bf16(af[m], bf[n], acc[m][n], 0, 0, 0);
    __builtin_amdgcn_s_setprio(0);

    __builtin_amdgcn_s_barrier();
    __builtin_amdgcn_sched_barrier(0);
  }

  #pragma unroll
  for (int m = 0; m < 4; ++m)
    #pragma unroll
    for (int n = 0; n < 2; ++n) {
      const int i = i0 + wr * 64 + m * 16 + fq * 4;
      const int e = e0 + wc * 32 + n * 16 + fr;
      const float be = bias[e];
      #pragma unroll
      for (int g = 0; g < 4; ++g)
        y[(size_t)(b * T_ + i + g) * NE_ + e] = acc[m][n][g] + be;
    }
}

// ---------------------------------------------------------------------------
// Kernel 2: att[b][i][j*4+h] = softmax_j(cooc[t_i, t_j, h]) + eye  (bf16)
// ---------------------------------------------------------------------------
__global__ __launch_bounds__(64) void softmax_k(
    const int* __restrict__ x, const float* __restrict__ cooc,
    unsigned short* __restrict__ att) {
  const int bi = blockIdx.x;
  const int b = bi >> 9, i = bi & (T_ - 1);
  const int lane = threadIdx.x;
  const int ti = x[b * T_ + i];
  const float* crow = cooc + (size_t)ti * D_;

  float w[8][4];
  #pragma unroll
  for (int r = 0; r < 8; ++r) {
    const int j = lane + r * 64;
    const int tj = x[b * T_ + j];
    const float4 v = *(const float4*)(crow + (size_t)tj * H_);
    w[r][0] = v.x; w[r][1] = v.y; w[r][2] = v.z; w[r][3] = v.w;
  }
  float m[4] = {-1e30f, -1e30f, -1e30f, -1e30f};
  #pragma unroll
  for (int r = 0; r < 8; ++r)
    #pragma unroll
    for (int h = 0; h < 4; ++h) m[h] = fmaxf(m[h], w[r][h]);
  #pragma unroll
  for (int off = 32; off > 0; off >>= 1)
    #pragma unroll
    for (int h = 0; h < 4; ++h) m[h] = fmaxf(m[h], __shfl_xor(m[h], off));
  float s[4] = {0.f, 0.f, 0.f, 0.f};
  #pragma unroll
  for (int r = 0; r < 8; ++r)
    #pragma unroll
    for (int h = 0; h < 4; ++h) { w[r][h] = __expf(w[r][h] - m[h]); s[h] += w[r][h]; }
  #pragma unroll
  for (int off = 32; off > 0; off >>= 1)
    #pragma unroll
    for (int h = 0; h < 4; ++h) s[h] += __shfl_xor(s[h], off);
  float inv[4];
  #pragma unroll
  for (int h = 0; h < 4; ++h) inv[h] = 1.f / s[h];

  unsigned short* arow = att + (size_t)(b * T_ + i) * (T_ * H_);
  #pragma unroll
  for (int r = 0; r < 8; ++r) {
    const int j = lane + r * 64;
    const float d = (j == i) ? 1.f : 0.f;
    ushort4 o;
    o.x = f2bf(w[r][0] * inv[0] + d);
    o.y = f2bf(w[r][1] * inv[1] + d);
    o.z = f2bf(w[r][2] * inv[2] + d);
    o.w = f2bf(w[r][3] * inv[3] + d);
    *(ushort4*)(arow + (size_t)j * H_) = o;
  }
}

// ---------------------------------------------------------------------------
// Round-1 fallback kernels (tiny ws)
// ---------------------------------------------------------------------------
__global__ __launch_bounds__(256) void gemm1_k(
    const float* __restrict__ pw, const float* __restrict__ cooc,
    unsigned short* __restrict__ mtT) {
  __shared__ unsigned short As[128 * 32];
  __shared__ unsigned short Bs[64 * 32];
  const int h  = blockIdx.z;
  const int e0 = blockIdx.x * 128;
  const int t0 = blockIdx.y * 64;
  const int tid  = threadIdx.x;
  const int lane = tid & 63, wave = tid >> 6;
  const int wr = wave >> 1, wc = wave & 1;
  const int fr = lane & 15, fq = lane >> 4;

  f32x4 acc[4][2];
  #pragma unroll
  for (int m = 0; m < 4; ++m)
    #pragma unroll
    for (int n = 0; n < 2; ++n) acc[m][n] = (f32x4){0.f, 0.f, 0.f, 0.f};

  const float* aB = pw + (size_t)e0 * PWROW + (size_t)h * D_;
  const float* bB = cooc + (size_t)t0 * D_;

  for (int k0 = 0; k0 < D_; k0 += 32) {
    __syncthreads();
    #pragma unroll
    for (int c = 0; c < 4; ++c) {
      const int fe = (c * 256 + tid) * 4;
      const int row = fe >> 5, k = fe & 31;
      const float4 v = *(const float4*)(aB + (size_t)row * PWROW + k0 + k);
      ushort4 o; o.x = f2bf(v.x); o.y = f2bf(v.y); o.z = f2bf(v.z); o.w = f2bf(v.w);
      *(ushort4*)&As[fe] = o;
    }
    #pragma unroll
    for (int c = 0; c < 2; ++c) {
      const int fe = (c * 256 + tid) * 4;
      const int row = fe >> 5, k = fe & 31;
      const float4 v = *(const float4*)(bB + (size_t)row * D_ + k0 + k);
      ushort4 o; o.x = f2bf(v.x); o.y = f2bf(v.y); o.z = f2bf(v.z); o.w = f2bf(v.w);
      *(ushort4*)&Bs[fe] = o;
    }
    __syncthreads();
    bf16x8 af[4], bf[2];
    #pragma unroll
    for (int m = 0; m < 4; ++m)
      af[m] = *(const bf16x8*)&As[(wr * 64 + m * 16 + fr) * 32 + fq * 8];
    #pragma unroll
    for (int n = 0; n < 2; ++n)
      bf[n] = *(const bf16x8*)&Bs[(wc * 32 + n * 16 + fr) * 32 + fq * 8];
    #pragma unroll
    for (int m = 0; m < 4; ++m)
      #pragma unroll
      for (int n = 0; n < 2; ++n)
        acc[m][n] = __builtin_amdgcn_mfma_f32_16x16x32_bf16(af[m], bf[n], acc[m][n], 0, 0, 0);
  }
  #pragma unroll
  for (int m = 0; m < 4; ++m)
    #pragma unroll
    for (int n = 0; n < 2; ++n) {
      const int e = e0 + wr * 64 + m * 16 + fq * 4;
      const int t = t0 + wc * 32 + n * 16 + fr;
      #pragma unroll
      for (int g = 0; g < 4; ++g)
        mtT[(size_t)(e + g) * D_ + t * H_ + h] = f2bf(acc[m][n][g]);
    }
}

__global__ __launch_bounds__(256) void gemm3_k(
    const unsigned short* __restrict__ att, const unsigned short* __restrict__ mtT,
    const int* __restrict__ x, const float* __restrict__ bias,
    float* __restrict__ y) {
  __shared__ unsigned short As[64 * 32];
  __shared__ unsigned short Bs[128 * 32];
  const int b  = blockIdx.z;
  const int i0 = blockIdx.x * 64;
  const int e0 = blockIdx.y * 128;
  const int tid  = threadIdx.x;
  const int lane = tid & 63, wave = tid >> 6;
  const int wr = wave >> 1, wc = wave & 1;
  const int fr = lane & 15, fq = lane >> 4;

  f32x4 acc[2][4];
  #pragma unroll
  for (int m = 0; m < 2; ++m)
    #pragma unroll
    for (int n = 0; n < 4; ++n) acc[m][n] = (f32x4){0.f, 0.f, 0.f, 0.f};

  const unsigned short* aB = att + (size_t)(b * T_ + i0) * (T_ * H_);

  for (int ks = 0; ks < 64; ++ks) {
    const int k0 = ks * 32;
    __syncthreads();
    {
      const int fe = tid * 8;
      const int row = fe >> 5, k = fe & 31;
      const uint4 v = *(const uint4*)(aB + (size_t)row * (T_ * H_) + k0 + k);
      *(uint4*)&As[fe] = v;
    }
    #pragma unroll
    for (int c = 0; c < 4; ++c) {
      const int q = c * 256 + tid;
      const int n = q >> 3, j8 = q & 7;
      const int tj = x[b * T_ + ks * 8 + j8];
      const uint2 v = *(const uint2*)(mtT + (size_t)(e0 + n) * D_ + tj * H_);
      *(uint2*)&Bs[n * 32 + j8 * 4] = v;
    }
    __syncthreads();
    bf16x8 af[2], bf[4];
    #pragma unroll
    for (int m = 0; m < 2; ++m)
      af[m] = *(const bf16x8*)&As[(wr * 32 + m * 16 + fr) * 32 + fq * 8];
    #pragma unroll
    for (int n = 0; n < 4; ++n)
      bf[n] = *(const bf16x8*)&Bs[(wc * 64 + n * 16 + fr) * 32 + fq * 8];
    #pragma unroll
    for (int m = 0; m < 2; ++m)
      #pragma unroll
      for (int n = 0; n < 4; ++n)
        acc[m][n] = __builtin_amdgcn_mfma_f32_16x16x32_bf16(af[m], bf[n], acc[m][n], 0, 0, 0);
  }
  #pragma unroll
  for (int m = 0; m < 2; ++m)
    #pragma unroll
    for (int n = 0; n < 4; ++n) {
      const int i = i0 + wr * 32 + m * 16 + fq * 4;
      const int e = e0 + wc * 64 + n * 16 + fr;
      const float be = bias[e];
      #pragma unroll
      for (int g = 0; g < 4; ++g)
        y[(size_t)(b * T_ + i + g) * NE_ + e] = acc[m][n][g] + be;
    }
}

// ---------------------------------------------------------------------------
extern "C" void kernel_launch(void* const* d_in, const int* in_sizes, int n_in,
                              void* d_out, int out_size, void* d_ws, size_t ws_size,
                              hipStream_t stream) {
  const int*   x    = (const int*)d_in[0];
  const float* cooc = (const float*)d_in[1];
  const float* pw   = (const float*)d_in[2];
  const float* pb   = (const float*)d_in[3];
  float* y = (float*)d_out;

  const size_t BQ_E = (size_t)V_ * D_;           // 16777216
  const size_t AQ_E = (size_t)M1 * D_;           // 25165824

  unsigned short* mtT = (unsigned short*)d_ws;   // == P0
  auto need = [&](int c) { return ((size_t)c * MTT_E + BQ_E + AQ_E) * 2; };

  int nz = 0;
  if      (ws_size >= need(4)) nz = 4;   // proven gemm1p (384 blocks)
  else if (ws_size >= need(2)) nz = 2;   // gemm1f
  else if (ws_size >= need(1)) nz = 1;

  if (nz >= 1) {
    unsigned short* Bq  = mtT + (size_t)nz * MTT_E;
    unsigned short* Aq  = Bq + BQ_E;
    unsigned short* GT  = Bq;   // alias: valid after gemm1
    unsigned short* att = Aq;   // alias: valid after gemm1
    hipLaunchKernelGGL(cvtAB_k, dim3(2048), dim3(256), 0, stream,
                       cooc, pw, Bq, (int)(BQ_E / 4), (int)((BQ_E + AQ_E) / 4));
    if (nz == 4)
      hipLaunchKernelGGL(gemm1p_k, dim3(M1 / 256, V_ / 256, 4), dim3(512), 0,
                         stream, Aq, Bq, mtT, D_ / 4);
    else
      hipLaunchKernelGGL(gemm1f_k, dim3(M1 / 128, V_ / 128, nz), dim3(256), 0,
                         stream, Aq, Bq, mtT, D_ / nz);
    hipLaunchKernelGGL(softmax_k, dim3(B_ * T_), dim3(64), 0, stream, x, cooc, att);
    hipLaunchKernelGGL(rgather_k, dim3(NE_), dim3(256), 0, stream, mtT, x, GT, nz);
    hipLaunchKernelGGL(gemm3d_k, dim3(T_ / 128, NE_ / 64, B_), dim3(256), 0, stream,
                       att, GT, pb, y);
  } else {
    unsigned short* att = mtT + MTT_E;
    hipLaunchKernelGGL(gemm1_k, dim3(NE_ / 128, V_ / 64, H_), dim3(256), 0, stream,
                       pw, cooc, mtT);
    hipLaunchKernelGGL(softmax_k, dim3(B_ * T_), dim3(64), 0, stream, x, cooc, att);
    hipLaunchKernelGGL(gemm3_k, dim3(T_ / 64, NE_ / 128, B_), dim3(256), 0, stream,
                       att, mtT, x, pb, y);
  }
}

// Round 14
// 229.828 us; speedup vs baseline: 1.0159x; 1.0136x over previous
//
#include <hip/hip_runtime.h>
#include <stdint.h>

// Problem constants
#define B_    8
#define T_    512
#define V_    2048
#define H_    4
#define NE_   768
#define D_    8192      // V_*H_
#define PWROW 32768     // V_*H_*H_
#define M1    3072      // NE_*H_
#define K3    2048      // T_*H_
#define MTT_E 6291456UL // NE_*D_

#define AS1 __attribute__((address_space(1)))
#define AS3 __attribute__((address_space(3)))

typedef __attribute__((ext_vector_type(8))) short bf16x8;
typedef __attribute__((ext_vector_type(4))) float f32x4;

__device__ __forceinline__ unsigned short f2bf(float f) {
  union { float f; unsigned int u; } c; c.f = f;
  unsigned int u = c.u;
  return (unsigned short)((u + 0x7FFFu + ((u >> 16) & 1u)) >> 16);
}
__device__ __forceinline__ float bf2f(unsigned short s) {
  union { unsigned int u; float f; } c; c.u = ((unsigned int)s) << 16;
  return c.f;
}

// ---------------------------------------------------------------------------
// fp32 -> bf16 convert of BOTH inputs in one launch.
// dst layout: [Bq (from cooc)][Aq (from pw)] contiguous.
// ---------------------------------------------------------------------------
__global__ __launch_bounds__(256) void cvtAB_k(
    const float* __restrict__ cooc, const float* __restrict__ pw,
    unsigned short* __restrict__ dst, int bq4, int n4) {
  int i = blockIdx.x * 256 + threadIdx.x;
  const int stride = gridDim.x * 256;
  for (; i < n4; i += stride) {
    const float4 v = (i < bq4) ? ((const float4*)cooc)[i]
                               : ((const float4*)pw)[i - bq4];
    ushort4 o;
    o.x = f2bf(v.x); o.y = f2bf(v.y); o.z = f2bf(v.z); o.w = f2bf(v.w);
    ((ushort4*)dst)[i] = o;
  }
}

// ---------------------------------------------------------------------------
// Kernel 1 (pipelined 256x256 2-phase, PROVEN round-6/8 @114us): C[m][t]
// over K-slice z. 8 waves (2M x 4N), BK=64, 128KB LDS double-buffer,
// global_load_lds 16B staging, counted vmcnt(8) (loads span barriers),
// chunk-XOR swizzle on both sides, setprio around MFMA.
// OCCUPANCY NOTE (r13 lesson): block is LDS-capped to 1/CU -> grid must be
// an exact multiple of 256. nz=8 -> 768 blocks = 3 exact rounds (114us);
// nz=4 -> 384 = 1.5 rounds -> 25% tail imbalance (129us). Use nz=8.
// Structure note (r12): LDS-BW-bound; 4 schedule variants all 114-134us.
// Register note (r9): at 2-waves/SIMD reg cap; no reg-staged operands.
// Output: partial z in mtT scatter layout [e][t*4+h], bf16 ushort4 stores.
// ---------------------------------------------------------------------------
__global__ __launch_bounds__(512, 2) void gemm1p_k(
    const unsigned short* __restrict__ Aq,   // [3072][8192]
    const unsigned short* __restrict__ Bq,   // [2048][8192]
    unsigned short* __restrict__ P,          // partials, z-strided by MTT_E
    int kk_per) {
  __shared__ unsigned short lds[2][2][256 * 64];   // [dbuf][A=0/B=1] 128 KB
  const int r0 = blockIdx.x * 256;   // m
  const int t0 = blockIdx.y * 256;   // t
  const int z  = blockIdx.z;
  const int kbeg = z * kk_per;
  const int NT = kk_per / 64;
  const int tid  = threadIdx.x;
  const int lane = tid & 63, w = tid >> 6;
  const int wm = w >> 2, wn = w & 3;
  const int fr = lane & 15, fq = lane >> 4;
  unsigned short* __restrict__ Pz = P + (size_t)z * MTT_E;

  f32x4 acc[8][4];
  #pragma unroll
  for (int m = 0; m < 8; ++m)
    #pragma unroll
    for (int n = 0; n < 4; ++n) acc[m][n] = (f32x4){0.f, 0.f, 0.f, 0.f};

  auto STAGE = [&](int d, int k0) {
    #pragma unroll
    for (int i = 0; i < 4; ++i) {
      const int q   = (w * 4 + i) * 64 + lane;
      const int row = q >> 3;
      const int c16 = (q & 7) ^ (row & 7);
      __builtin_amdgcn_global_load_lds(
          (const AS1 void*)(Aq + (size_t)(r0 + row) * D_ + k0 + c16 * 8),
          (AS3 void*)(&lds[d][0][(w * 4 + i) * 512]), 16, 0, 0);
    }
    #pragma unroll
    for (int i = 0; i < 4; ++i) {
      const int q   = (w * 4 + i) * 64 + lane;
      const int row = q >> 3;
      const int c16 = (q & 7) ^ (row & 7);
      __builtin_amdgcn_global_load_lds(
          (const AS1 void*)(Bq + (size_t)(t0 + row) * D_ + k0 + c16 * 8),
          (AS3 void*)(&lds[d][1][(w * 4 + i) * 512]), 16, 0, 0);
    }
  };
  #define OFFS(r, c) ((r) * 64 + (((c) ^ ((r) & 7)) * 8))

  STAGE(0, kbeg);

  for (int kt = 0; kt < NT; ++kt) {
    if (kt + 1 < NT) {
      STAGE((kt + 1) & 1, kbeg + (kt + 1) * 64);
      asm volatile("s_waitcnt vmcnt(8)" ::: "memory");   // stage(kt) landed
    } else {
      asm volatile("s_waitcnt vmcnt(0)" ::: "memory");
    }
    __builtin_amdgcn_s_barrier();
    __builtin_amdgcn_sched_barrier(0);

    const unsigned short* Ab = &lds[kt & 1][0][0];
    const unsigned short* Bb = &lds[kt & 1][1][0];

    bf16x8 afA[4][2], afB[4][2], bf0[2][2], bf1[2][2];
    #pragma unroll
    for (int m = 0; m < 4; ++m)
      #pragma unroll
      for (int kk = 0; kk < 2; ++kk)
        afA[m][kk] = *(const bf16x8*)&Ab[OFFS(wm * 128 + m * 16 + fr, kk * 4 + fq)];
    #pragma unroll
    for (int n = 0; n < 2; ++n)
      #pragma unroll
      for (int kk = 0; kk < 2; ++kk) {
        bf0[n][kk] = *(const bf16x8*)&Bb[OFFS(wn * 64 + n * 16 + fr, kk * 4 + fq)];
        bf1[n][kk] = *(const bf16x8*)&Bb[OFFS(wn * 64 + 32 + n * 16 + fr, kk * 4 + fq)];
      }

    __builtin_amdgcn_s_setprio(1);
    #pragma unroll
    for (int m = 0; m < 4; ++m)
      #pragma unroll
      for (int n = 0; n < 2; ++n)
        #pragma unroll
        for (int kk = 0; kk < 2; ++kk) {
          acc[m][n]     = __builtin_amdgcn_mfma_f32_16x16x32_bf16(afA[m][kk], bf0[n][kk], acc[m][n], 0, 0, 0);
          acc[m][n + 2] = __builtin_amdgcn_mfma_f32_16x16x32_bf16(afA[m][kk], bf1[n][kk], acc[m][n + 2], 0, 0, 0);
        }
    #pragma unroll
    for (int m = 0; m < 4; ++m)
      #pragma unroll
      for (int kk = 0; kk < 2; ++kk)
        afB[m][kk] = *(const bf16x8*)&Ab[OFFS(wm * 128 + 64 + m * 16 + fr, kk * 4 + fq)];
    #pragma unroll
    for (int m = 0; m < 4; ++m)
      #pragma unroll
      for (int n = 0; n < 2; ++n)
        #pragma unroll
        for (int kk = 0; kk < 2; ++kk) {
          acc[m + 4][n]     = __builtin_amdgcn_mfma_f32_16x16x32_bf16(afB[m][kk], bf0[n][kk], acc[m + 4][n], 0, 0, 0);
          acc[m + 4][n + 2] = __builtin_amdgcn_mfma_f32_16x16x32_bf16(afB[m][kk], bf1[n][kk], acc[m + 4][n + 2], 0, 0, 0);
        }
    __builtin_amdgcn_s_setprio(0);

    __builtin_amdgcn_s_barrier();
    __builtin_amdgcn_sched_barrier(0);
  }
  #undef OFFS

  #pragma unroll
  for (int m = 0; m < 8; ++m)
    #pragma unroll
    for (int n = 0; n < 4; ++n) {
      const int rbase = r0 + wm * 128 + m * 16 + fq * 4;
      const int t = t0 + wn * 64 + n * 16 + fr;
      ushort4 o;
      o.x = f2bf(acc[m][n][0]); o.y = f2bf(acc[m][n][1]);
      o.z = f2bf(acc[m][n][2]); o.w = f2bf(acc[m][n][3]);
      *(ushort4*)&Pz[(size_t)(rbase >> 2) * D_ + t * H_] = o;
    }
}

// ---------------------------------------------------------------------------
// Kernel 1 (m97 structure, proven): used when ws only fits nz<=2.
// ---------------------------------------------------------------------------
__global__ __launch_bounds__(256) void gemm1f_k(
    const unsigned short* __restrict__ Aq,
    const unsigned short* __restrict__ Bq,
    unsigned short* __restrict__ P, int kk) {
  __shared__ unsigned short As[128 * 32];
  __shared__ unsigned short Bs[128 * 32];
  const int r0 = blockIdx.x * 128;
  const int t0 = blockIdx.y * 128;
  const int z  = blockIdx.z;
  const int kbeg = z * kk, kend = kbeg + kk;
  const int tid  = threadIdx.x;
  const int lane = tid & 63, wave = tid >> 6;
  const int wr = wave >> 1, wc = wave & 1;
  const int fr = lane & 15, fq = lane >> 4;
  const int l4 = lane >> 2, lb = lane & 3;
  unsigned short* __restrict__ Pz = P + (size_t)z * MTT_E;

  f32x4 acc[4][4];
  #pragma unroll
  for (int m = 0; m < 4; ++m)
    #pragma unroll
    for (int n = 0; n < 4; ++n) acc[m][n] = (f32x4){0.f, 0.f, 0.f, 0.f};

  for (int k0 = kbeg; k0 < kend; k0 += 32) {
    __syncthreads();
    #pragma unroll
    for (int c = 0; c < 2; ++c) {
      const int ch  = wave * 2 + c;
      const int row = ch * 16 + l4;
      __builtin_amdgcn_global_load_lds(
          (const AS1 void*)(Aq + (size_t)(r0 + row) * D_ + k0 + lb * 8),
          (AS3 void*)(As + ch * 512), 16, 0, 0);
      __builtin_amdgcn_global_load_lds(
          (const AS1 void*)(Bq + (size_t)(t0 + row) * D_ + k0 + lb * 8),
          (AS3 void*)(Bs + ch * 512), 16, 0, 0);
    }
    __syncthreads();
    bf16x8 af[4], bf[4];
    #pragma unroll
    for (int m = 0; m < 4; ++m)
      af[m] = *(const bf16x8*)&As[(wr * 64 + m * 16 + fr) * 32 + fq * 8];
    #pragma unroll
    for (int n = 0; n < 4; ++n)
      bf[n] = *(const bf16x8*)&Bs[(wc * 64 + n * 16 + fr) * 32 + fq * 8];
    #pragma unroll
    for (int m = 0; m < 4; ++m)
      #pragma unroll
      for (int n = 0; n < 4; ++n)
        acc[m][n] = __builtin_amdgcn_mfma_f32_16x16x32_bf16(af[m], bf[n], acc[m][n], 0, 0, 0);
  }
  #pragma unroll
  for (int m = 0; m < 4; ++m)
    #pragma unroll
    for (int n = 0; n < 4; ++n) {
      const int rbase = r0 + wr * 64 + m * 16 + fq * 4;
      const int t = t0 + wc * 64 + n * 16 + fr;
      ushort4 o;
      o.x = f2bf(acc[m][n][0]); o.y = f2bf(acc[m][n][1]);
      o.z = f2bf(acc[m][n][2]); o.w = f2bf(acc[m][n][3]);
      *(ushort4*)&Pz[(size_t)(rbase >> 2) * D_ + t * H_] = o;
    }
}

// ---------------------------------------------------------------------------
// Fused reduce+gather, LDS-staged (proven round-8).
// ---------------------------------------------------------------------------
__global__ __launch_bounds__(256) void rgather_k(
    const unsigned short* __restrict__ P, const int* __restrict__ x,
    unsigned short* __restrict__ GT, int nz) {
  __shared__ int toks[B_ * T_];          // 16 KB
  __shared__ unsigned short row[D_];     // 16 KB
  const int tid = threadIdx.x;
  #pragma unroll
  for (int c = 0; c < 16; ++c) toks[c * 256 + tid] = x[c * 256 + tid];

  const int e = blockIdx.x;
  const unsigned short* prow = P + (size_t)e * D_;

  float s[8][4];
  #pragma unroll
  for (int i = 0; i < 8; ++i) { s[i][0] = s[i][1] = s[i][2] = s[i][3] = 0.f; }
  for (int z = 0; z < nz; ++z) {
    const unsigned short* pz = prow + (size_t)z * MTT_E;
    #pragma unroll
    for (int i = 0; i < 8; ++i) {
      const ushort4 v = *(const ushort4*)(pz + (size_t)(i * 256 + tid) * 4);
      s[i][0] += bf2f(v.x); s[i][1] += bf2f(v.y);
      s[i][2] += bf2f(v.z); s[i][3] += bf2f(v.w);
    }
  }
  #pragma unroll
  for (int i = 0; i < 8; ++i) {
    ushort4 o;
    o.x = f2bf(s[i][0]); o.y = f2bf(s[i][1]);
    o.z = f2bf(s[i][2]); o.w = f2bf(s[i][3]);
    *(ushort4*)&row[(i * 256 + tid) * 4] = o;
  }
  __syncthreads();

  const int lane = tid & 63, wave = tid >> 6;
  #pragma unroll
  for (int bb = 0; bb < 2; ++bb) {
    const int b = wave * 2 + bb;
    unsigned short* grow = GT + ((size_t)b * NE_ + e) * K3;
    const int* tb = toks + b * T_;
    #pragma unroll
    for (int r = 0; r < 8; ++r) {
      const int j = r * 64 + lane;
      const uint2 v = *(const uint2*)&row[tb[j] * H_];
      *(uint2*)(grow + j * H_) = v;
    }
  }
}

// ---------------------------------------------------------------------------
// Kernel 3 (dbuf + counted vmcnt, r13): y[b][i][e] = sum_k att*GT + pb.
// ---------------------------------------------------------------------------
__global__ __launch_bounds__(256) void gemm3d_k(
    const unsigned short* __restrict__ att,  // [B*T][2048]
    const unsigned short* __restrict__ GT,   // [B][768][2048]
    const float* __restrict__ bias,
    float* __restrict__ y) {
  __shared__ unsigned short As[2][128 * 32];
  __shared__ unsigned short Bs[2][64 * 32];
  const int b  = blockIdx.z;
  const int i0 = blockIdx.x * 128;
  const int e0 = blockIdx.y * 64;
  const int tid  = threadIdx.x;
  const int lane = tid & 63, wave = tid >> 6;
  const int wr = wave >> 1, wc = wave & 1;
  const int fr = lane & 15, fq = lane >> 4;

  f32x4 acc[4][2];
  #pragma unroll
  for (int m = 0; m < 4; ++m)
    #pragma unroll
    for (int n = 0; n < 2; ++n) acc[m][n] = (f32x4){0.f, 0.f, 0.f, 0.f};

  const unsigned short* aB = att + (size_t)(b * T_ + i0) * K3;
  const unsigned short* bB = GT + ((size_t)b * NE_ + e0) * K3;

  auto STAGE = [&](int d, int k0) {
    #pragma unroll
    for (int rdi = 0; rdi < 2; ++rdi) {
      const int q = rdi * 256 + tid;
      const int row = q >> 2, koff = (q & 3) * 8;
      __builtin_amdgcn_global_load_lds(
          (const AS1 void*)(aB + (size_t)row * K3 + k0 + koff),
          (AS3 void*)(&As[d][q * 8]), 16, 0, 0);
    }
    {
      const int q = tid;
      const int row = q >> 2, koff = (q & 3) * 8;
      __builtin_amdgcn_global_load_lds(
          (const AS1 void*)(bB + (size_t)row * K3 + k0 + koff),
          (AS3 void*)(&Bs[d][q * 8]), 16, 0, 0);
    }
  };

  STAGE(0, 0);

  for (int kt = 0; kt < 64; ++kt) {
    if (kt + 1 < 64) {
      STAGE((kt + 1) & 1, (kt + 1) * 32);
      asm volatile("s_waitcnt vmcnt(3)" ::: "memory");   // tile kt landed
    } else {
      asm volatile("s_waitcnt vmcnt(0)" ::: "memory");
    }
    __builtin_amdgcn_s_barrier();
    __builtin_amdgcn_sched_barrier(0);

    const unsigned short* Ab = &As[kt & 1][0];
    const unsigned short* Bb = &Bs[kt & 1][0];
    bf16x8 af[4], bf[2];
    #pragma unroll
    for (int m = 0; m < 4; ++m)
      af[m] = *(const bf16x8*)&Ab[(wr * 64 + m * 16 + fr) * 32 + fq * 8];
    #pragma unroll
    for (int n = 0; n < 2; ++n)
      bf[n] = *(const bf16x8*)&Bb[(wc * 32 + n * 16 + fr) * 32 + fq * 8];

    __builtin_amdgcn_s_setprio(1);
    #pragma unroll
    for (int m = 0; m < 4; ++m)
      #pragma unroll
      for (int n = 0; n < 2; ++n)
        acc[m][n] = __builtin_amdgcn_mfma_f32_16x16x32_bf16(af[m], bf[n], acc[m][n], 0, 0, 0);
    __builtin_amdgcn_s_setprio(0);

    __builtin_amdgcn_s_barrier();
    __builtin_amdgcn_sched_barrier(0);
  }

  #pragma unroll
  for (int m = 0; m < 4; ++m)
    #pragma unroll
    for (int n = 0; n < 2; ++n) {
      const int i = i0 + wr * 64 + m * 16 + fq * 4;
      const int e = e0 + wc * 32 + n * 16 + fr;
      const float be = bias[e];
      #pragma unroll
      for (int g = 0; g < 4; ++g)
        y[(size_t)(b * T_ + i + g) * NE_ + e] = acc[m][n][g] + be;
    }
}

// ---------------------------------------------------------------------------
// Kernel 2: att[b][i][j*4+h] = softmax_j(cooc[t_i, t_j, h]) + eye  (bf16)
// ---------------------------------------------------------------------------
__global__ __launch_bounds__(64) void softmax_k(
    const int* __restrict__ x, const float* __restrict__ cooc,
    unsigned short* __restrict__ att) {
  const int bi = blockIdx.x;
  const int b = bi >> 9, i = bi & (T_ - 1);
  const int lane = threadIdx.x;
  const int ti = x[b * T_ + i];
  const float* crow = cooc + (size_t)ti * D_;

  float w[8][4];
  #pragma unroll
  for (int r = 0; r < 8; ++r) {
    const int j = lane + r * 64;
    const int tj = x[b * T_ + j];
    const float4 v = *(const float4*)(crow + (size_t)tj * H_);
    w[r][0] = v.x; w[r][1] = v.y; w[r][2] = v.z; w[r][3] = v.w;
  }
  float m[4] = {-1e30f, -1e30f, -1e30f, -1e30f};
  #pragma unroll
  for (int r = 0; r < 8; ++r)
    #pragma unroll
    for (int h = 0; h < 4; ++h) m[h] = fmaxf(m[h], w[r][h]);
  #pragma unroll
  for (int off = 32; off > 0; off >>= 1)
    #pragma unroll
    for (int h = 0; h < 4; ++h) m[h] = fmaxf(m[h], __shfl_xor(m[h], off));
  float s[4] = {0.f, 0.f, 0.f, 0.f};
  #pragma unroll
  for (int r = 0; r < 8; ++r)
    #pragma unroll
    for (int h = 0; h < 4; ++h) { w[r][h] = __expf(w[r][h] - m[h]); s[h] += w[r][h]; }
  #pragma unroll
  for (int off = 32; off > 0; off >>= 1)
    #pragma unroll
    for (int h = 0; h < 4; ++h) s[h] += __shfl_xor(s[h], off);
  float inv[4];
  #pragma unroll
  for (int h = 0; h < 4; ++h) inv[h] = 1.f / s[h];

  unsigned short* arow = att + (size_t)(b * T_ + i) * (T_ * H_);
  #pragma unroll
  for (int r = 0; r < 8; ++r) {
    const int j = lane + r * 64;
    const float d = (j == i) ? 1.f : 0.f;
    ushort4 o;
    o.x = f2bf(w[r][0] * inv[0] + d);
    o.y = f2bf(w[r][1] * inv[1] + d);
    o.z = f2bf(w[r][2] * inv[2] + d);
    o.w = f2bf(w[r][3] * inv[3] + d);
    *(ushort4*)(arow + (size_t)j * H_) = o;
  }
}

// ---------------------------------------------------------------------------
// Round-1 fallback kernels (tiny ws)
// ---------------------------------------------------------------------------
__global__ __launch_bounds__(256) void gemm1_k(
    const float* __restrict__ pw, const float* __restrict__ cooc,
    unsigned short* __restrict__ mtT) {
  __shared__ unsigned short As[128 * 32];
  __shared__ unsigned short Bs[64 * 32];
  const int h  = blockIdx.z;
  const int e0 = blockIdx.x * 128;
  const int t0 = blockIdx.y * 64;
  const int tid  = threadIdx.x;
  const int lane = tid & 63, wave = tid >> 6;
  const int wr = wave >> 1, wc = wave & 1;
  const int fr = lane & 15, fq = lane >> 4;

  f32x4 acc[4][2];
  #pragma unroll
  for (int m = 0; m < 4; ++m)
    #pragma unroll
    for (int n = 0; n < 2; ++n) acc[m][n] = (f32x4){0.f, 0.f, 0.f, 0.f};

  const float* aB = pw + (size_t)e0 * PWROW + (size_t)h * D_;
  const float* bB = cooc + (size_t)t0 * D_;

  for (int k0 = 0; k0 < D_; k0 += 32) {
    __syncthreads();
    #pragma unroll
    for (int c = 0; c < 4; ++c) {
      const int fe = (c * 256 + tid) * 4;
      const int row = fe >> 5, k = fe & 31;
      const float4 v = *(const float4*)(aB + (size_t)row * PWROW + k0 + k);
      ushort4 o; o.x = f2bf(v.x); o.y = f2bf(v.y); o.z = f2bf(v.z); o.w = f2bf(v.w);
      *(ushort4*)&As[fe] = o;
    }
    #pragma unroll
    for (int c = 0; c < 2; ++c) {
      const int fe = (c * 256 + tid) * 4;
      const int row = fe >> 5, k = fe & 31;
      const float4 v = *(const float4*)(bB + (size_t)row * D_ + k0 + k);
      ushort4 o; o.x = f2bf(v.x); o.y = f2bf(v.y); o.z = f2bf(v.z); o.w = f2bf(v.w);
      *(ushort4*)&Bs[fe] = o;
    }
    __syncthreads();
    bf16x8 af[4], bf[2];
    #pragma unroll
    for (int m = 0; m < 4; ++m)
      af[m] = *(const bf16x8*)&As[(wr * 64 + m * 16 + fr) * 32 + fq * 8];
    #pragma unroll
    for (int n = 0; n < 2; ++n)
      bf[n] = *(const bf16x8*)&Bs[(wc * 32 + n * 16 + fr) * 32 + fq * 8];
    #pragma unroll
    for (int m = 0; m < 4; ++m)
      #pragma unroll
      for (int n = 0; n < 2; ++n)
        acc[m][n] = __builtin_amdgcn_mfma_f32_16x16x32_bf16(af[m], bf[n], acc[m][n], 0, 0, 0);
  }
  #pragma unroll
  for (int m = 0; m < 4; ++m)
    #pragma unroll
    for (int n = 0; n < 2; ++n) {
      const int e = e0 + wr * 64 + m * 16 + fq * 4;
      const int t = t0 + wc * 32 + n * 16 + fr;
      #pragma unroll
      for (int g = 0; g < 4; ++g)
        mtT[(size_t)(e + g) * D_ + t * H_ + h] = f2bf(acc[m][n][g]);
    }
}

__global__ __launch_bounds__(256) void gemm3_k(
    const unsigned short* __restrict__ att, const unsigned short* __restrict__ mtT,
    const int* __restrict__ x, const float* __restrict__ bias,
    float* __restrict__ y) {
  __shared__ unsigned short As[64 * 32];
  __shared__ unsigned short Bs[128 * 32];
  const int b  = blockIdx.z;
  const int i0 = blockIdx.x * 64;
  const int e0 = blockIdx.y * 128;
  const int tid  = threadIdx.x;
  const int lane = tid & 63, wave = tid >> 6;
  const int wr = wave >> 1, wc = wave & 1;
  const int fr = lane & 15, fq = lane >> 4;

  f32x4 acc[2][4];
  #pragma unroll
  for (int m = 0; m < 2; ++m)
    #pragma unroll
    for (int n = 0; n < 4; ++n) acc[m][n] = (f32x4){0.f, 0.f, 0.f, 0.f};

  const unsigned short* aB = att + (size_t)(b * T_ + i0) * (T_ * H_);

  for (int ks = 0; ks < 64; ++ks) {
    const int k0 = ks * 32;
    __syncthreads();
    {
      const int fe = tid * 8;
      const int row = fe >> 5, k = fe & 31;
      const uint4 v = *(const uint4*)(aB + (size_t)row * (T_ * H_) + k0 + k);
      *(uint4*)&As[fe] = v;
    }
    #pragma unroll
    for (int c = 0; c < 4; ++c) {
      const int q = c * 256 + tid;
      const int n = q >> 3, j8 = q & 7;
      const int tj = x[b * T_ + ks * 8 + j8];
      const uint2 v = *(const uint2*)(mtT + (size_t)(e0 + n) * D_ + tj * H_);
      *(uint2*)&Bs[n * 32 + j8 * 4] = v;
    }
    __syncthreads();
    bf16x8 af[2], bf[4];
    #pragma unroll
    for (int m = 0; m < 2; ++m)
      af[m] = *(const bf16x8*)&As[(wr * 32 + m * 16 + fr) * 32 + fq * 8];
    #pragma unroll
    for (int n = 0; n < 4; ++n)
      bf[n] = *(const bf16x8*)&Bs[(wc * 64 + n * 16 + fr) * 32 + fq * 8];
    #pragma unroll
    for (int m = 0; m < 2; ++m)
      #pragma unroll
      for (int n = 0; n < 4; ++n)
        acc[m][n] = __builtin_amdgcn_mfma_f32_16x16x32_bf16(af[m], bf[n], acc[m][n], 0, 0, 0);
  }
  #pragma unroll
  for (int m = 0; m < 2; ++m)
    #pragma unroll
    for (int n = 0; n < 4; ++n) {
      const int i = i0 + wr * 32 + m * 16 + fq * 4;
      const int e = e0 + wc * 64 + n * 16 + fr;
      const float be = bias[e];
      #pragma unroll
      for (int g = 0; g < 4; ++g)
        y[(size_t)(b * T_ + i + g) * NE_ + e] = acc[m][n][g] + be;
    }
}

// ---------------------------------------------------------------------------
extern "C" void kernel_launch(void* const* d_in, const int* in_sizes, int n_in,
                              void* d_out, int out_size, void* d_ws, size_t ws_size,
                              hipStream_t stream) {
  const int*   x    = (const int*)d_in[0];
  const float* cooc = (const float*)d_in[1];
  const float* pw   = (const float*)d_in[2];
  const float* pb   = (const float*)d_in[3];
  float* y = (float*)d_out;

  const size_t BQ_E = (size_t)V_ * D_;           // 16777216
  const size_t AQ_E = (size_t)M1 * D_;           // 25165824

  unsigned short* mtT = (unsigned short*)d_ws;   // == P0
  auto need = [&](int c) { return ((size_t)c * MTT_E + BQ_E + AQ_E) * 2; };

  int nz = 0;
  if      (ws_size >= need(8)) nz = 8;   // gemm1p, 768 blocks = 3 exact rounds
  else if (ws_size >= need(4)) nz = 4;   // gemm1p, 1.5 rounds (slower)
  else if (ws_size >= need(2)) nz = 2;   // gemm1f
  else if (ws_size >= need(1)) nz = 1;

  if (nz >= 1) {
    unsigned short* Bq  = mtT + (size_t)nz * MTT_E;
    unsigned short* Aq  = Bq + BQ_E;
    unsigned short* GT  = Bq;   // alias: valid after gemm1
    unsigned short* att = Aq;   // alias: valid after gemm1
    hipLaunchKernelGGL(cvtAB_k, dim3(2048), dim3(256), 0, stream,
                       cooc, pw, Bq, (int)(BQ_E / 4), (int)((BQ_E + AQ_E) / 4));
    if (nz >= 4)
      hipLaunchKernelGGL(gemm1p_k, dim3(M1 / 256, V_ / 256, nz), dim3(512), 0,
                         stream, Aq, Bq, mtT, D_ / nz);
    else
      hipLaunchKernelGGL(gemm1f_k, dim3(M1 / 128, V_ / 128, nz), dim3(256), 0,
                         stream, Aq, Bq, mtT, D_ / nz);
    hipLaunchKernelGGL(softmax_k, dim3(B_ * T_), dim3(64), 0, stream, x, cooc, att);
    hipLaunchKernelGGL(rgather_k, dim3(NE_), dim3(256), 0, stream, mtT, x, GT, nz);
    hipLaunchKernelGGL(gemm3d_k, dim3(T_ / 128, NE_ / 64, B_), dim3(256), 0, stream,
                       att, GT, pb, y);
  } else {
    unsigned short* att = mtT + MTT_E;
    hipLaunchKernelGGL(gemm1_k, dim3(NE_ / 128, V_ / 64, H_), dim3(256), 0, stream,
                       pw, cooc, mtT);
    hipLaunchKernelGGL(softmax_k, dim3(B_ * T_), dim3(64), 0, stream, x, cooc, att);
    hipLaunchKernelGGL(gemm3_k, dim3(T_ / 64, NE_ / 128, B_), dim3(256), 0, stream,
                       att, mtT, x, pb, y);
  }
}